// Round 4
// baseline (546.252 us; speedup 1.0000x reference)
//
#include <hip/hip_runtime.h>
#include <stdint.h>

typedef _Float16 f16;
typedef _Float16 f16x4 __attribute__((ext_vector_type(4)));
typedef _Float16 f16x8 __attribute__((ext_vector_type(8)));
typedef float f32x4 __attribute__((ext_vector_type(4)));

#define D_DIM 256
#define K_CB 4096
#define N_ROWS 65536
#define BM 128
#define BN 128
#define N_TILES 32
#define LOSS_OFF 16777216
#define IDS_OFF 16777217

// workspace layout (bytes)
#define WS_CHI 0            // 4096*256 f16 = 2 MB
#define WS_CN 2097152       // 4096 f32 = 16 KB
#define WS_FLAGS 2113536    // 65536 u32 = 256 KB

// direct-to-LDS 16B async copy (per-lane global addr, wave-uniform LDS base + lane*16)
#define GL_LDS(g, s_) __builtin_amdgcn_global_load_lds( \
    (const __attribute__((address_space(1))) void*)(g), \
    (__attribute__((address_space(3))) void*)(s_), 16, 0, 0)

static __device__ __forceinline__ uint32_t f2u(float x) { union { float f; uint32_t u; } c; c.f = x; return c.u; }
static __device__ __forceinline__ float u2f(uint32_t x) { union { float f; uint32_t u; } c; c.u = x; return c.f; }
static __device__ __forceinline__ uint32_t umin(uint32_t a, uint32_t b) { return a < b ? a : b; }
static __device__ __forceinline__ uint32_t umax(uint32_t a, uint32_t b) { return a > b ? a : b; }

// ---------------- K0: codebook -> f16 hi + fp32 row norms; zero flags + loss slot ----
__global__ __launch_bounds__(256) void k_prep_cb(const float* __restrict__ cb,
                                                 f16* __restrict__ chi,
                                                 float* __restrict__ cn,
                                                 uint32_t* __restrict__ flags,
                                                 float* __restrict__ loss_slot) {
    const int tid = threadIdx.x;
    const int w = tid >> 6, l = tid & 63;
    const int row = blockIdx.x * 4 + w;            // one wave per codebook row
    const float4 v = ((const float4*)cb)[row * 64 + l];
    f16x4 h4;
    h4[0] = (f16)v.x; h4[1] = (f16)v.y; h4[2] = (f16)v.z; h4[3] = (f16)v.w;
    float ss = v.x * v.x + v.y * v.y + v.z * v.z + v.w * v.w;
#pragma unroll
    for (int m = 32; m >= 1; m >>= 1) ss += __shfl_xor(ss, m);
    ((f16x4*)chi)[row * 64 + l] = h4;
    if (l == 0) cn[row] = ss;
    // 1024 blocks x 64 slots covers all 65536 flags (each written 4x, w=0..3 — benign)
    flags[blockIdx.x * 64 + (tid & 63)] = 0;
    if (blockIdx.x == 0 && tid == 0) *loss_slot = 0.0f;
}

// ---------------- K1: 1-pass f16 hi GEMM + top-3 tracking + exact top-2 rescore ----
// LDS (81920 B dynamic):
//   [0,65536)       A_hi : 128 rows x 256 f16, 16B blocks XOR-swizzled by (row&7)
//   [65536,81920)   B dbuf: 2 x 8192 B (128 entries x 32 f16), swizzled by ((e>>1)&3)
//   B region reused after main loop: mk1/mk2/mk3 u32[128] each, then loss scratch.
__global__ __launch_bounds__(256) void k_main(const float* __restrict__ z,
                                              const float* __restrict__ cb,
                                              const f16* __restrict__ chi,
                                              const float* __restrict__ cn,
                                              uint32_t* __restrict__ flags,
                                              float* __restrict__ out) {
    extern __shared__ char smem[];
    const int tid = threadIdx.x;
    const int w = tid >> 6, l = tid & 63;
    const int wm = w >> 1, wn = w & 1;             // 2x2 wave grid, 64x64 tiles
    const int l15 = l & 15, qh = l >> 4;
    const int blk = blockIdx.x;
    const float* ztile = z + (size_t)blk * (BM * D_DIM);

    // ---- stage A once: fp32 -> f16 hi, swizzled ----
#pragma unroll 4
    for (int p = 0; p < 32; ++p) {
        const int r = p * 4 + w;
        const float4 v = ((const float4*)ztile)[r * 64 + l];
        f16x4 h4;
        h4[0] = (f16)v.x; h4[1] = (f16)v.y; h4[2] = (f16)v.z; h4[3] = (f16)v.w;
        const int addr = r * 512 + ((((l >> 1) ^ (r & 7))) << 4) + ((l & 1) << 3);
        *(f16x4*)(smem + addr) = h4;
    }

    // ---- codebook-norm prefetch (tile 0) ----
    float cnNext[4];
#pragma unroll
    for (int j = 0; j < 4; ++j) cnNext[j] = cn[wn * 64 + j * 16 + l15];

    // ---- B staging constants ----
    const int e0 = tid >> 2;
    const int q0 = (tid & 3) ^ ((e0 >> 1) & 3);
    const int offE = e0 * 256 + q0 * 8;

    // ---- fragment read address constants ----
    int rowb[4], rs[4], bcon[4];
#pragma unroll
    for (int i = 0; i < 4; ++i) {
        const int r = wm * 64 + i * 16 + l15;
        rowb[i] = r * 512;
        rs[i] = r & 7;
    }
#pragma unroll
    for (int j = 0; j < 4; ++j) {
        const int e = wn * 64 + j * 16 + l15;
        bcon[j] = e * 64 + ((qh ^ ((e >> 1) & 3)) << 4);
    }

    // prologue: B chunk for step 0 into buf0
    {
        const f16* gh = chi + offE;
        char* bb = smem + 65536 + w * 1024;
        GL_LDS(gh, bb);
        GL_LDS(gh + 16384, bb + 4096);
    }

    uint32_t k1[16], k2[16], k3[16];
#pragma unroll
    for (int s = 0; s < 16; ++s) { k1[s] = 0xFFFFFFFFu; k2[s] = 0xFFFFFFFFu; k3[s] = 0xFFFFFFFFu; }
    f32x4 acc[4][4];
    float cnCur[4];

    for (int tile = 0; tile < N_TILES; ++tile) {
#pragma unroll
        for (int j = 0; j < 4; ++j) cnCur[j] = cnNext[j];
#pragma unroll
        for (int i = 0; i < 4; ++i)
#pragma unroll
            for (int j = 0; j < 4; ++j) acc[i][j] = (f32x4){0.f, 0.f, 0.f, 0.f};
#pragma unroll
        for (int kc = 0; kc < 8; ++kc) {
            __syncthreads();
            const int step = tile * 8 + kc;
            if (step + 1 < N_TILES * 8) {
                const int nt = (step + 1) >> 3, nk = (step + 1) & 7;
                const f16* gh = chi + nt * (BN * D_DIM) + nk * 32 + offE;
                char* bb = smem + 65536 + ((step + 1) & 1) * 8192 + w * 1024;
                GL_LDS(gh, bb);
                GL_LDS(gh + 16384, bb + 4096);
            }
            if (kc == 0) {
                const int tn = (tile + 1 < N_TILES) ? tile + 1 : tile;
#pragma unroll
                for (int j = 0; j < 4; ++j)
                    cnNext[j] = cn[tn * BN + wn * 64 + j * 16 + l15];
            }
            const char* bbase = smem + 65536 + (step & 1) * 8192;
            f16x8 ah[4], bh[4];
#pragma unroll
            for (int i = 0; i < 4; ++i) {
                const int t = ((kc << 2) + qh) ^ rs[i];
                ah[i] = *(const f16x8*)(smem + rowb[i] + (t << 4));
            }
#pragma unroll
            for (int j = 0; j < 4; ++j) bh[j] = *(const f16x8*)(bbase + bcon[j]);
#pragma unroll
            for (int i = 0; i < 4; ++i)
#pragma unroll
                for (int j = 0; j < 4; ++j)
                    acc[i][j] = __builtin_amdgcn_mfma_f32_16x16x32_f16(ah[i], bh[j], acc[i][j], 0, 0, 0);
        }
        // epilogue: d' = cn - 2*M (>=0 clamped), key = (bits & ~0xFFF) | col, top-3 insert
        const int colb = tile * BN + wn * 64 + l15;
#pragma unroll
        for (int j = 0; j < 4; ++j) {
            const uint32_t col = (uint32_t)(colb + j * 16);
            const float cnj = cnCur[j];
#pragma unroll
            for (int i = 0; i < 4; ++i)
#pragma unroll
                for (int rr = 0; rr < 4; ++rr) {
                    const int s = i * 4 + rr;
                    float d = fmaf(acc[i][j][rr], -2.0f, cnj);
                    d = fmaxf(d, 0.0f);
                    const uint32_t kk = (f2u(d) & 0xFFFFF000u) | col;
                    const uint32_t t2 = umax(k1[s], kk); k1[s] = umin(k1[s], kk);
                    const uint32_t t3 = umax(k2[s], t2); k2[s] = umin(k2[s], t2);
                    k3[s] = umin(k3[s], t3);
                }
        }
    }

    // ---- merge sorted triples across the 16 column-lanes of each row ----
#pragma unroll
    for (int s = 0; s < 16; ++s) {
        uint32_t a1 = k1[s], a2 = k2[s], a3 = k3[s];
#pragma unroll
        for (int m = 1; m <= 8; m <<= 1) {
            const uint32_t b1 = (uint32_t)__shfl_xor((int)a1, m);
            const uint32_t b2 = (uint32_t)__shfl_xor((int)a2, m);
            const uint32_t b3 = (uint32_t)__shfl_xor((int)a3, m);
            const uint32_t x = umax(a1, b1);
            const uint32_t m2v = umin(a2, b2), M2 = umax(a2, b2);
            const uint32_t m3v = umin(a3, b3);
            a1 = umin(a1, b1);
            a2 = umin(x, m2v);
            a3 = umin(umin(umax(x, m2v), M2), m3v);
        }
        k1[s] = a1; k2[s] = a2; k3[s] = a3;
    }
    __syncthreads();                               // B region reusable now
    uint32_t* mk = (uint32_t*)(smem + 65536);      // mk1[128] | mk2[128] | mk3[128]
    double* lossW = (double*)(smem + 65536 + 1536);
    if (wn == 0 && l15 == 0) {
#pragma unroll
        for (int s = 0; s < 16; ++s) {
            const int row = wm * 64 + (s >> 2) * 16 + qh * 4 + (s & 3);
            mk[row] = k1[s]; mk[128 + row] = k2[s]; mk[256 + row] = k3[s];
        }
    }
    __syncthreads();
    if (wn == 1 && l15 == 0) {
#pragma unroll
        for (int s = 0; s < 16; ++s) {
            const int row = wm * 64 + (s >> 2) * 16 + qh * 4 + (s & 3);
            const uint32_t b1 = mk[row], b2 = mk[128 + row], b3 = mk[256 + row];
            const uint32_t x = umax(k1[s], b1);
            const uint32_t m2v = umin(k2[s], b2), M2 = umax(k2[s], b2);
            const uint32_t m3v = umin(k3[s], b3);
            mk[row] = umin(k1[s], b1);
            mk[128 + row] = umin(x, m2v);
            mk[256 + row] = umin(umin(umax(x, m2v), M2), m3v);
        }
    }
    __syncthreads();

    // ---- gather + exact f64 rescore of top-2 + certification + loss ----
    double lossAcc = 0.0;
    for (int it = 0; it < 32; ++it) {
        const int row = it * 4 + w;                // one wave per row
        const uint32_t K1 = mk[row], K2 = mk[128 + row], K3 = mk[256 + row];
        const int col1 = (int)(K1 & 4095u), col2 = (int)(K2 & 4095u);
        const float4 c1 = ((const float4*)cb)[col1 * 64 + l];
        const float4 c2 = ((const float4*)cb)[col2 * 64 + l];
        const float4 z4 = ((const float4*)ztile)[row * 64 + l];
        double e1, e2;
        {
            const double dx1 = (double)c1.x - z4.x, dy1 = (double)c1.y - z4.y;
            const double dz1 = (double)c1.z - z4.z, dw1 = (double)c1.w - z4.w;
            e1 = dx1 * dx1 + dy1 * dy1 + dz1 * dz1 + dw1 * dw1;
            const double dx2 = (double)c2.x - z4.x, dy2 = (double)c2.y - z4.y;
            const double dz2 = (double)c2.z - z4.z, dw2 = (double)c2.w - z4.w;
            e2 = dx2 * dx2 + dy2 * dy2 + dz2 * dz2 + dw2 * dw2;
        }
        float zn2 = z4.x * z4.x + z4.y * z4.y + z4.z * z4.z + z4.w * z4.w;
#pragma unroll
        for (int m = 32; m >= 1; m >>= 1) {
            e1 += __shfl_xor(e1, m);
            e2 += __shfl_xor(e2, m);
            zn2 += __shfl_xor(zn2, m);
        }
        const bool take1 = (e1 < e2) || (e1 == e2 && col1 <= col2);
        const float4 cw = take1 ? c1 : c2;
        ((float4*)out)[(blk * BM + row) * 64 + l] = cw;
        if (l == 0) {
            const int colw = take1 ? col1 : col2;
            const double ew = take1 ? e1 : e2;
            out[IDS_OFF + blk * BM + row] = (float)colw;
            lossAcc += ew;
            const float d3 = u2f(K3 & 0xFFFFF000u) + zn2;   // lower bound of 3rd-best approx d2
            const float eps = 0.006f * sqrtf(zn2) + 0.01f;
            if (!((float)ew < d3 - eps)) flags[blk * BM + row] = 1u;
        }
    }
    if (l == 0) lossW[w] = lossAcc;
    __syncthreads();
    if (tid == 0) {
        const double tot = (lossW[0] + lossW[1] + lossW[2] + lossW[3]) * (1.25 / 16777216.0);
        atomicAdd(out + LOSS_OFF, (float)tot);
    }
}

// ---------------- K2: exact fixup for uncertified rows (rare) ----
__global__ __launch_bounds__(256) void k_fix(const float* __restrict__ z,
                                             const float* __restrict__ cb,
                                             const uint32_t* __restrict__ flags,
                                             float* __restrict__ out) {
    __shared__ float zrow[256];
    __shared__ double d2s[4096];
    __shared__ double bestVal[256];
    __shared__ int bestIdx[256];
    __shared__ uint32_t fl[128];
    __shared__ uint32_t anyflag;
    const int tid = threadIdx.x;
    const int rb = blockIdx.x * 128;
    if (tid == 0) anyflag = 0;
    __syncthreads();
    if (tid < 128) {
        const uint32_t f = flags[rb + tid];
        fl[tid] = f;
        if (f) anyflag = 1;                        // benign race: any writer sets 1
    }
    __syncthreads();
    if (anyflag == 0) return;
    for (int rr = 0; rr < 128; ++rr) {
        if (fl[rr] == 0) continue;                 // uniform branch (fl in LDS)
        const int row = rb + rr;
        __syncthreads();
        if (tid < 64) ((float4*)zrow)[tid] = ((const float4*)z)[row * 64 + tid];
        __syncthreads();
        double bv = 1.0e300; int bi = 0;
        for (int c0 = 0; c0 < 16; ++c0) {
            const int c = c0 * 256 + tid;
            const float4* crow = (const float4*)(cb + (size_t)c * 256);
            double s = 0.0;
            for (int q = 0; q < 64; ++q) {
                const float4 cv = crow[q];
                const float4 zv = ((const float4*)zrow)[q];
                const double dx = (double)cv.x - zv.x, dy = (double)cv.y - zv.y;
                const double dz = (double)cv.z - zv.z, dw = (double)cv.w - zv.w;
                s += dx * dx + dy * dy + dz * dz + dw * dw;
            }
            d2s[c] = s;
            if (s < bv) { bv = s; bi = c; }        // c ascending per thread -> first-index ties
        }
        bestVal[tid] = bv; bestIdx[tid] = bi;
        __syncthreads();
        if (tid == 0) {
            double v = bestVal[0]; int ix = bestIdx[0];
            for (int t = 1; t < 256; ++t) {
                if (bestVal[t] < v || (bestVal[t] == v && bestIdx[t] < ix)) { v = bestVal[t]; ix = bestIdx[t]; }
            }
            bestIdx[0] = ix;
        }
        __syncthreads();
        const int newc = bestIdx[0];
        const int oldc = (int)out[IDS_OFF + row];
        if (newc != oldc) {
            if (tid < 64)
                ((float4*)out)[row * 64 + tid] = ((const float4*)(cb + (size_t)newc * 256))[tid];
            if (tid == 0) {
                out[IDS_OFF + row] = (float)newc;
                atomicAdd(out + LOSS_OFF, (float)((d2s[newc] - d2s[oldc]) * (1.25 / 16777216.0)));
            }
        }
        __syncthreads();
    }
}

extern "C" void kernel_launch(void* const* d_in, const int* in_sizes, int n_in,
                              void* d_out, int out_size, void* d_ws, size_t ws_size,
                              hipStream_t stream) {
    (void)in_sizes; (void)n_in; (void)out_size; (void)ws_size;
    const float* z = (const float*)d_in[0];
    const float* cb = (const float*)d_in[1];
    float* out = (float*)d_out;
    char* ws = (char*)d_ws;
    f16* chi = (f16*)(ws + WS_CHI);
    float* cn = (float*)(ws + WS_CN);
    uint32_t* flags = (uint32_t*)(ws + WS_FLAGS);

    hipFuncSetAttribute((const void*)k_main,
                        hipFuncAttributeMaxDynamicSharedMemorySize, 81920);

    k_prep_cb<<<K_CB / 4, 256, 0, stream>>>(cb, chi, cn, flags, out + LOSS_OFF);
    k_main<<<N_ROWS / BM, 256, 81920, stream>>>(z, cb, chi, cn, flags, out);
    k_fix<<<N_ROWS / 128, 256, 0, stream>>>(z, cb, flags, out);
}

// Round 5
// 304.179 us; speedup vs baseline: 1.7958x; 1.7958x over previous
//
#include <hip/hip_runtime.h>
#include <stdint.h>

typedef _Float16 f16;
typedef _Float16 f16x4 __attribute__((ext_vector_type(4)));
typedef _Float16 f16x8 __attribute__((ext_vector_type(8)));
typedef float f32x4 __attribute__((ext_vector_type(4)));
typedef unsigned long long u64;

#define D_DIM 256
#define K_CB 4096
#define N_ROWS 65536
#define BM 128
#define BN 128
#define N_TILES 32
#define LOSS_OFF 16777216
#define IDS_OFF 16777217
#define MAX_FIX 4096

// workspace layout (bytes)
#define WS_CHI 0            // 4096*256 f16 = 2 MB
#define WS_CN 2097152       // 4096 f32 = 16 KB
#define WS_CNT 2113536      // u32 counter (+pad to 64)
#define WS_ROWS 2113600     // 4096 u32 = 16 KB
#define WS_SLOTS 2129984    // 4096 u64 = 32 KB

// direct-to-LDS 16B async copy (per-lane global addr, wave-uniform LDS base + lane*16)
#define GL_LDS(g, s_) __builtin_amdgcn_global_load_lds( \
    (const __attribute__((address_space(1))) void*)(g), \
    (__attribute__((address_space(3))) void*)(s_), 16, 0, 0)

static __device__ __forceinline__ uint32_t f2u(float x) { union { float f; uint32_t u; } c; c.f = x; return c.u; }
static __device__ __forceinline__ float u2f(uint32_t x) { union { float f; uint32_t u; } c; c.u = x; return c.f; }
static __device__ __forceinline__ uint32_t umin_(uint32_t a, uint32_t b) { return a < b ? a : b; }
static __device__ __forceinline__ uint32_t umax_(uint32_t a, uint32_t b) { return a > b ? a : b; }
static __device__ __forceinline__ u64 d2u(double x) { union { double d; u64 u; } c; c.d = x; return c.u; }

// ---------------- K0: codebook -> f16 hi + fp32 row norms; init cnt/slots/loss ----
__global__ __launch_bounds__(256) void k_prep_cb(const float* __restrict__ cb,
                                                 f16* __restrict__ chi,
                                                 float* __restrict__ cn,
                                                 uint32_t* __restrict__ cnt,
                                                 u64* __restrict__ slots,
                                                 float* __restrict__ loss_slot) {
    const int tid = threadIdx.x;
    const int w = tid >> 6, l = tid & 63;
    const int row = blockIdx.x * 4 + w;            // one wave per codebook row
    const float4 v = ((const float4*)cb)[row * 64 + l];
    f16x4 h4;
    h4[0] = (f16)v.x; h4[1] = (f16)v.y; h4[2] = (f16)v.z; h4[3] = (f16)v.w;
    float ss = v.x * v.x + v.y * v.y + v.z * v.z + v.w * v.w;
#pragma unroll
    for (int m = 32; m >= 1; m >>= 1) ss += __shfl_xor(ss, m);
    ((f16x4*)chi)[row * 64 + l] = h4;
    if (l == 0) cn[row] = ss;
    if (tid < 4) slots[blockIdx.x * 4 + tid] = 0xFFFFFFFFFFFFFFFFull;  // 1024 blocks x 4 = 4096
    if (blockIdx.x == 0 && tid == 0) { *cnt = 0; *loss_slot = 0.0f; }
}

// ---------------- K1: 1-pass f16 GEMM (A = -2*z_hi, C-init = cn+64) + top-3 + rescore ----
// LDS (81920 B dynamic):
//   [0,65536)       A : 128 rows x 256 f16 (-2*z), 16B blocks XOR-swizzled by (row&7)
//   [65536,81920)   B dbuf: 2 x 8192 B (128 entries x 32 f16), swizzled by ((e>>1)&3)
//   B region reused after main loop: mk1/mk2/mk3 u32[128], then loss scratch.
__global__ __launch_bounds__(256) void k_main(const float* __restrict__ z,
                                              const float* __restrict__ cb,
                                              const f16* __restrict__ chi,
                                              const float* __restrict__ cn,
                                              uint32_t* __restrict__ cnt,
                                              uint32_t* __restrict__ rows,
                                              float* __restrict__ out) {
    extern __shared__ char smem[];
    const int tid = threadIdx.x;
    const int w = tid >> 6, l = tid & 63;
    const int wm = w >> 1, wn = w & 1;             // 2x2 wave grid, 64x64 tiles
    const int l15 = l & 15, qh = l >> 4;
    const int blk = blockIdx.x;
    const float* ztile = z + (size_t)blk * (BM * D_DIM);

    // ---- stage A once: fp32 -> f16(-2z), swizzled ----
#pragma unroll 4
    for (int p = 0; p < 32; ++p) {
        const int r = p * 4 + w;
        const float4 v = ((const float4*)ztile)[r * 64 + l];
        f16x4 h4;
        h4[0] = (f16)(v.x * -2.0f); h4[1] = (f16)(v.y * -2.0f);
        h4[2] = (f16)(v.z * -2.0f); h4[3] = (f16)(v.w * -2.0f);
        const int addr = r * 512 + ((((l >> 1) ^ (r & 7))) << 4) + ((l & 1) << 3);
        *(f16x4*)(smem + addr) = h4;
    }

    // ---- codebook-norm prefetch (tile 0) ----
    float cnNext[4];
#pragma unroll
    for (int j = 0; j < 4; ++j) cnNext[j] = cn[wn * 64 + j * 16 + l15];

    // ---- B staging constants ----
    const int e0 = tid >> 2;
    const int q0 = (tid & 3) ^ ((e0 >> 1) & 3);
    const int offE = e0 * 256 + q0 * 8;

    // ---- fragment read address constants ----
    int rowb[4], rs[4], bcon[4];
#pragma unroll
    for (int i = 0; i < 4; ++i) {
        const int r = wm * 64 + i * 16 + l15;
        rowb[i] = r * 512;
        rs[i] = r & 7;
    }
#pragma unroll
    for (int j = 0; j < 4; ++j) {
        const int e = wn * 64 + j * 16 + l15;
        bcon[j] = e * 64 + ((qh ^ ((e >> 1) & 3)) << 4);
    }

    // prologue: B chunk for step 0 into buf0
    {
        const f16* gh = chi + offE;
        char* bb = smem + 65536 + w * 1024;
        GL_LDS(gh, bb);
        GL_LDS(gh + 16384, bb + 4096);
    }

    uint32_t k1[16], k2[16], k3[16];
#pragma unroll
    for (int s = 0; s < 16; ++s) { k1[s] = 0xFFFFFFFFu; k2[s] = 0xFFFFFFFFu; k3[s] = 0xFFFFFFFFu; }
    f32x4 acc[4][4];
    float cnCur[4];

    for (int tile = 0; tile < N_TILES; ++tile) {
#pragma unroll
        for (int j = 0; j < 4; ++j) cnCur[j] = cnNext[j];
        // C-init = cn + 64 -> final acc = cn + 64 - 2*z.c  (positive; key-packable)
#pragma unroll
        for (int j = 0; j < 4; ++j) {
            const float base = cnCur[j] + 64.0f;
#pragma unroll
            for (int i = 0; i < 4; ++i) acc[i][j] = (f32x4){base, base, base, base};
        }
#pragma unroll
        for (int kc = 0; kc < 8; ++kc) {
            __syncthreads();
            const int step = tile * 8 + kc;
            if (step + 1 < N_TILES * 8) {
                const int nt = (step + 1) >> 3, nk = (step + 1) & 7;
                const f16* gh = chi + nt * (BN * D_DIM) + nk * 32 + offE;
                char* bb = smem + 65536 + ((step + 1) & 1) * 8192 + w * 1024;
                GL_LDS(gh, bb);
                GL_LDS(gh + 16384, bb + 4096);
            }
            if (kc == 0) {
                const int tn = (tile + 1 < N_TILES) ? tile + 1 : tile;
#pragma unroll
                for (int j = 0; j < 4; ++j)
                    cnNext[j] = cn[tn * BN + wn * 64 + j * 16 + l15];
            }
            const char* bbase = smem + 65536 + (step & 1) * 8192;
            f16x8 ah[4], bh[4];
#pragma unroll
            for (int i = 0; i < 4; ++i) {
                const int t = ((kc << 2) + qh) ^ rs[i];
                ah[i] = *(const f16x8*)(smem + rowb[i] + (t << 4));
            }
#pragma unroll
            for (int j = 0; j < 4; ++j) bh[j] = *(const f16x8*)(bbase + bcon[j]);
#pragma unroll
            for (int i = 0; i < 4; ++i)
#pragma unroll
                for (int j = 0; j < 4; ++j)
                    acc[i][j] = __builtin_amdgcn_mfma_f32_16x16x32_f16(ah[i], bh[j], acc[i][j], 0, 0, 0);
        }
        // epilogue: key = (bits(acc) & ~0xFFF) | col; 6-op top-3 insert per candidate
        const int colb = tile * BN + wn * 64 + l15;
#pragma unroll
        for (int j = 0; j < 4; ++j) {
            const uint32_t col = (uint32_t)(colb + j * 16);
#pragma unroll
            for (int i = 0; i < 4; ++i)
#pragma unroll
                for (int rr = 0; rr < 4; ++rr) {
                    const int s = i * 4 + rr;
                    const uint32_t kk = (f2u(acc[i][j][rr]) & 0xFFFFF000u) | col;
                    const uint32_t t2 = umax_(k1[s], kk); k1[s] = umin_(k1[s], kk);
                    const uint32_t t3 = umax_(k2[s], t2); k2[s] = umin_(k2[s], t2);
                    k3[s] = umin_(k3[s], t3);
                }
        }
    }

    // ---- merge sorted triples across the 16 column-lanes of each row ----
#pragma unroll
    for (int s = 0; s < 16; ++s) {
        uint32_t a1 = k1[s], a2 = k2[s], a3 = k3[s];
#pragma unroll
        for (int m = 1; m <= 8; m <<= 1) {
            const uint32_t b1 = (uint32_t)__shfl_xor((int)a1, m);
            const uint32_t b2 = (uint32_t)__shfl_xor((int)a2, m);
            const uint32_t b3 = (uint32_t)__shfl_xor((int)a3, m);
            const uint32_t x = umax_(a1, b1);
            const uint32_t m2v = umin_(a2, b2), M2 = umax_(a2, b2);
            const uint32_t m3v = umin_(a3, b3);
            a1 = umin_(a1, b1);
            a2 = umin_(x, m2v);
            a3 = umin_(umin_(umax_(x, m2v), M2), m3v);
        }
        k1[s] = a1; k2[s] = a2; k3[s] = a3;
    }
    __syncthreads();                               // B region reusable now
    uint32_t* mk = (uint32_t*)(smem + 65536);      // mk1[128] | mk2[128] | mk3[128]
    double* lossW = (double*)(smem + 65536 + 1536);
    if (wn == 0 && l15 == 0) {
#pragma unroll
        for (int s = 0; s < 16; ++s) {
            const int row = wm * 64 + (s >> 2) * 16 + qh * 4 + (s & 3);
            mk[row] = k1[s]; mk[128 + row] = k2[s]; mk[256 + row] = k3[s];
        }
    }
    __syncthreads();
    if (wn == 1 && l15 == 0) {
#pragma unroll
        for (int s = 0; s < 16; ++s) {
            const int row = wm * 64 + (s >> 2) * 16 + qh * 4 + (s & 3);
            const uint32_t b1 = mk[row], b2 = mk[128 + row], b3 = mk[256 + row];
            const uint32_t x = umax_(k1[s], b1);
            const uint32_t m2v = umin_(k2[s], b2), M2 = umax_(k2[s], b2);
            const uint32_t m3v = umin_(k3[s], b3);
            mk[row] = umin_(k1[s], b1);
            mk[128 + row] = umin_(x, m2v);
            mk[256 + row] = umin_(umin_(umax_(x, m2v), M2), m3v);
        }
    }
    __syncthreads();

    // ---- gather + exact f64 rescore of top-2 + certification + loss ----
    double lossAcc = 0.0;
    for (int it = 0; it < 32; ++it) {
        const int row = it * 4 + w;                // one wave per row
        const uint32_t K1 = mk[row], K2 = mk[128 + row], K3 = mk[256 + row];
        const int col1 = (int)(K1 & 4095u), col2 = (int)(K2 & 4095u);
        const float4 c1 = ((const float4*)cb)[col1 * 64 + l];
        const float4 c2 = ((const float4*)cb)[col2 * 64 + l];
        const float4 z4 = ((const float4*)ztile)[row * 64 + l];
        double e1, e2;
        {
            const double dx1 = (double)c1.x - z4.x, dy1 = (double)c1.y - z4.y;
            const double dz1 = (double)c1.z - z4.z, dw1 = (double)c1.w - z4.w;
            e1 = dx1 * dx1 + dy1 * dy1 + dz1 * dz1 + dw1 * dw1;
            const double dx2 = (double)c2.x - z4.x, dy2 = (double)c2.y - z4.y;
            const double dz2 = (double)c2.z - z4.z, dw2 = (double)c2.w - z4.w;
            e2 = dx2 * dx2 + dy2 * dy2 + dz2 * dz2 + dw2 * dw2;
        }
        float zn2 = z4.x * z4.x + z4.y * z4.y + z4.z * z4.z + z4.w * z4.w;
#pragma unroll
        for (int m = 32; m >= 1; m >>= 1) {
            e1 += __shfl_xor(e1, m);
            e2 += __shfl_xor(e2, m);
            zn2 += __shfl_xor(zn2, m);
        }
        const bool take1 = (e1 < e2) || (e1 == e2 && col1 <= col2);
        const float4 cw = take1 ? c1 : c2;
        ((float4*)out)[(blk * BM + row) * 64 + l] = cw;
        if (l == 0) {
            const int colw = take1 ? col1 : col2;
            const double ew = take1 ? e1 : e2;
            out[IDS_OFF + blk * BM + row] = (float)colw;
            lossAcc += ew;
            // key = cn - 2M + 64 -> d2 lower bound of 3rd-best = key + zn - 64
            const float d3 = u2f(K3 & 0xFFFFF000u) + zn2 - 64.0f;
            const float eps = 0.006f * sqrtf(zn2) + 0.01f;
            if (!((float)ew < d3 - eps)) {
                const uint32_t e = atomicAdd(cnt, 1u);
                if (e < MAX_FIX) rows[e] = (uint32_t)(blk * BM + row);
            }
        }
    }
    if (l == 0) lossW[w] = lossAcc;
    __syncthreads();
    if (tid == 0) {
        const double tot = (lossW[0] + lossW[1] + lossW[2] + lossW[3]) * (1.25 / 16777216.0);
        atomicAdd(out + LOSS_OFF, (float)tot);
    }
}

// ---------------- K2a: parallel exact scan for flagged rows (16 blocks per row) ----
__global__ __launch_bounds__(256) void k_fix_scan(const float* __restrict__ z,
                                                  const float* __restrict__ cb,
                                                  const uint32_t* __restrict__ cnt,
                                                  const uint32_t* __restrict__ rows,
                                                  u64* __restrict__ slots) {
    __shared__ float zrow[256];
    __shared__ u64 wmin[4];
    const int tid = threadIdx.x;
    const int w = tid >> 6, l = tid & 63;
    const int chunk = blockIdx.x & 15;
    uint32_t n = *cnt; if (n > MAX_FIX) n = MAX_FIX;
    for (uint32_t e = blockIdx.x >> 4; e < n; e += 64) {
        const int row = (int)rows[e];
        __syncthreads();                           // protect zrow across iterations
        if (tid < 64) ((float4*)zrow)[tid] = ((const float4*)z)[row * 64 + tid];
        __syncthreads();
        const int c = chunk * 256 + tid;
        const float4* crow = (const float4*)(cb + (size_t)c * 256);
        double s = 0.0;
        for (int q = 0; q < 64; ++q) {
            const float4 cv = crow[q];
            const float4 zv = ((const float4*)zrow)[q];
            const double dx = (double)cv.x - zv.x, dy = (double)cv.y - zv.y;
            const double dz = (double)cv.z - zv.z, dw = (double)cv.w - zv.w;
            s += dx * dx + dy * dy + dz * dz + dw * dw;
        }
        u64 key = (d2u(s) & 0xFFFFFFFFFFFFF000ull) | (u64)c;  // d2 desc-trunc + col tiebreak
#pragma unroll
        for (int m = 32; m >= 1; m >>= 1) {
            const u64 o = __shfl_xor(key, m);
            if (o < key) key = o;
        }
        if (l == 0) wmin[w] = key;
        __syncthreads();
        if (tid == 0) {
            u64 k = wmin[0];
            if (wmin[1] < k) k = wmin[1];
            if (wmin[2] < k) k = wmin[2];
            if (wmin[3] < k) k = wmin[3];
            atomicMin(&slots[e], k);
        }
    }
}

// ---------------- K2b: patch ids / z_q / loss for flagged rows ----
__global__ __launch_bounds__(256) void k_fix_patch(const float* __restrict__ z,
                                                   const float* __restrict__ cb,
                                                   const uint32_t* __restrict__ cnt,
                                                   const uint32_t* __restrict__ rows,
                                                   const u64* __restrict__ slots,
                                                   float* __restrict__ out) {
    const int tid = threadIdx.x;
    uint32_t n = *cnt; if (n > MAX_FIX) n = MAX_FIX;
    for (uint32_t e = blockIdx.x; e < n; e += 256) {
        const int row = (int)rows[e];
        const int newc = (int)(slots[e] & 4095ull);
        const int oldc = (int)out[IDS_OFF + row];
        if (newc == oldc) continue;                // uniform across block
        double dOld = 0.0, dNew = 0.0;
        if (tid < 64) {
            const float4 zv = ((const float4*)z)[row * 64 + tid];
            const float4 co = ((const float4*)cb)[oldc * 64 + tid];
            const float4 cn4 = ((const float4*)cb)[newc * 64 + tid];
            const double ax = (double)co.x - zv.x, ay = (double)co.y - zv.y;
            const double az = (double)co.z - zv.z, aw = (double)co.w - zv.w;
            dOld = ax * ax + ay * ay + az * az + aw * aw;
            const double bx = (double)cn4.x - zv.x, by = (double)cn4.y - zv.y;
            const double bz = (double)cn4.z - zv.z, bw = (double)cn4.w - zv.w;
            dNew = bx * bx + by * by + bz * bz + bw * bw;
            ((float4*)out)[row * 64 + tid] = cn4;  // patch z_q
        }
#pragma unroll
        for (int m = 32; m >= 1; m >>= 1) {
            dOld += __shfl_xor(dOld, m);
            dNew += __shfl_xor(dNew, m);
        }
        if (tid == 0) {
            out[IDS_OFF + row] = (float)newc;
            atomicAdd(out + LOSS_OFF, (float)((dNew - dOld) * (1.25 / 16777216.0)));
        }
    }
}

extern "C" void kernel_launch(void* const* d_in, const int* in_sizes, int n_in,
                              void* d_out, int out_size, void* d_ws, size_t ws_size,
                              hipStream_t stream) {
    (void)in_sizes; (void)n_in; (void)out_size; (void)ws_size;
    const float* z = (const float*)d_in[0];
    const float* cb = (const float*)d_in[1];
    float* out = (float*)d_out;
    char* ws = (char*)d_ws;
    f16* chi = (f16*)(ws + WS_CHI);
    float* cn = (float*)(ws + WS_CN);
    uint32_t* cnt = (uint32_t*)(ws + WS_CNT);
    uint32_t* rows = (uint32_t*)(ws + WS_ROWS);
    u64* slots = (u64*)(ws + WS_SLOTS);

    hipFuncSetAttribute((const void*)k_main,
                        hipFuncAttributeMaxDynamicSharedMemorySize, 81920);

    k_prep_cb<<<K_CB / 4, 256, 0, stream>>>(cb, chi, cn, cnt, slots, out + LOSS_OFF);
    k_main<<<N_ROWS / BM, 256, 81920, stream>>>(z, cb, chi, cn, cnt, rows, out);
    k_fix_scan<<<1024, 256, 0, stream>>>(z, cb, cnt, rows, slots);
    k_fix_patch<<<256, 256, 0, stream>>>(z, cb, cnt, rows, slots, out);
}